// Round 9
// baseline (231.044 us; speedup 1.0000x reference)
//
#include <hip/hip_runtime.h>
#include <math.h>

typedef short bf16x8 __attribute__((ext_vector_type(8)));
typedef short bf16x4 __attribute__((ext_vector_type(4)));
typedef float f32x4  __attribute__((ext_vector_type(4)));

__device__ __forceinline__ unsigned short f2bf(float f) {
    union { float f; unsigned u; } v; v.f = f;
    unsigned r = v.u + 0x7FFFu + ((v.u >> 16) & 1u);   // RNE
    return (unsigned short)(r >> 16);
}

__device__ __forceinline__ unsigned cvt_pk_bf16(float a, float b) {
    unsigned r;
    asm("v_cvt_pk_bf16_f32 %0, %1, %2" : "=v"(r) : "v"(a), "v"(b));
    return r;   // lo16 = bf16(a), hi16 = bf16(b), RNE
}

// async global->LDS, 16B per lane, LDS dest = wave-uniform base + lane*16B
#define GLDS16(gp, lp) __builtin_amdgcn_global_load_lds( \
    (const __attribute__((address_space(1))) void*)(gp), \
    (__attribute__((address_space(3))) void*)(lp), 16, 0, 0)

// Head-dim permutation: MFMA-C position (nt*16+c) stored at byte position
// (c*4+nt) within each 64-wide head block. Q,K share pi (dot invariant);
// V/Ab use sigma; Wto compensates. Q additionally pre-scaled by 0.125.

// attn split-K chunk table (R18): 20 blocks/bh, max len 8.
// entry = i | start<<3 | len<<8 | slot<<12 | complete<<17. Heavy-first.
__device__ const unsigned XT[20] = {
    59399u, 63559u, 67719u, 71879u,          // i7: s0/8/16/24 len8 slots14-17
    30725u, 34885u, 39045u,                  // i5: s0/8/16    len8 slots7-9
    10243u, 14403u,                          // i3: s0/8       len8 slots2-3
    133121u,                                 // i1: s0 len8 complete
    42758u, 46910u, 51062u, 55214u,          // i6: s0/7/14/21 len7 slots10-13
    18180u, 22332u,                          // i4: s0/7 len7  slots4-5
    26228u,                                  // i4: s14 len6   slot6
    1538u, 5682u,                            // i2: s0/6 len6  slots0-1
    132096u                                  // i0: s0 len4 complete
};

// ---------------------------------------------------------------------------
// prep: z<4 -> W fp32 [k][n] -> Wt bf16 [n][k] (z=3 un-permutes sigma(pi));
//       z>=4 -> X fp32 -> bf16 copy-convert
// ---------------------------------------------------------------------------
__global__ __launch_bounds__(256)
void prep(const float* __restrict__ X, unsigned short* __restrict__ Xb,
          const float* __restrict__ w0, const float* __restrict__ w1,
          const float* __restrict__ w2, const float* __restrict__ w3,
          unsigned short* o0, unsigned short* o1,
          unsigned short* o2, unsigned short* o3)
{
    const int z = blockIdx.z;
    if (z >= 4) {
        const int lb = (z - 4) * 256 + blockIdx.y * 16 + blockIdx.x;
        const size_t t = (size_t)lb * 256 + threadIdx.x;
        const float4 a = *(const float4*)(X + t * 8);
        const float4 b = *(const float4*)(X + t * 8 + 4);
        unsigned short u[8] = { f2bf(a.x), f2bf(a.y), f2bf(a.z), f2bf(a.w),
                                f2bf(b.x), f2bf(b.y), f2bf(b.z), f2bf(b.w) };
        *(int4*)(Xb + t * 8) = *(int4*)u;
        return;
    }
    const float* W; unsigned short* O;
    switch (z) {
        case 0: W = w0; O = o0; break;
        case 1: W = w1; O = o1; break;
        case 2: W = w2; O = o2; break;
        default: W = w3; O = o3; break;
    }
    __shared__ float T[64][65];
    const int tid = threadIdx.x;
    const int n0 = blockIdx.x * 64, k0 = blockIdx.y * 64;
    #pragma unroll
    for (int i = 0; i < 4; i++) {
        const int k = (tid >> 4) + i * 16, n4 = (tid & 15) * 4;
        const float4 v = *(const float4*)(W + (size_t)(k0 + k) * 1024 + n0 + n4);
        T[k][n4] = v.x; T[k][n4+1] = v.y; T[k][n4+2] = v.z; T[k][n4+3] = v.w;
    }
    __syncthreads();
    if (z == 3) {
        #pragma unroll
        for (int i = 0; i < 4; i++) {
            const int n = (tid >> 4) + i * 16, k4 = (tid & 15) * 4;
            unsigned short u[4];
            #pragma unroll
            for (int j = 0; j < 4; j++) {
                const int q = k4 + j;                      // Ab storage pos
                const int p = (q & 3) * 16 + (q >> 2);     // inv sigma
                const int d = (p & 3) * 16 + (p >> 2);     // inv pi
                u[j] = f2bf(T[d][n]);
            }
            *(int2*)(O + (size_t)(n0 + n) * 1024 + k0 + k4) = *(int2*)u;
        }
    } else {
        #pragma unroll
        for (int i = 0; i < 4; i++) {
            const int n = (tid >> 4) + i * 16, k4 = (tid & 15) * 4;
            unsigned short u[4] = { f2bf(T[k4][n]), f2bf(T[k4+1][n]),
                                    f2bf(T[k4+2][n]), f2bf(T[k4+3][n]) };
            *(int2*)(O + (size_t)(n0 + n) * 1024 + k0 + k4) = *(int2*)u;
        }
    }
}

// ---------------------------------------------------------------------------
// QKV GEMM (R16, unchanged): 128x128 tile, 2-phase GLDS double-buffer,
// XOR slot-swizzle both-sides, one barrier per K-step.
// ---------------------------------------------------------------------------
__global__ __launch_bounds__(256)
void qkv_gemm(const unsigned short* __restrict__ Xb,
              const unsigned short* __restrict__ Wtq, const unsigned short* __restrict__ Wtk,
              const unsigned short* __restrict__ Wtv,
              const float* __restrict__ bq, const float* __restrict__ bk,
              const float* __restrict__ bv,
              unsigned short* __restrict__ Qb, unsigned short* __restrict__ Kb,
              unsigned short* __restrict__ Vtb)
{
    const unsigned short* Wt; const float* bias; unsigned short* Out;
    const int z = blockIdx.z;
    if (z == 0)      { Wt = Wtq; bias = bq; Out = Qb; }
    else if (z == 1) { Wt = Wtk; bias = bk; Out = Kb; }
    else             { Wt = Wtv; bias = bv; Out = Vtb; }

    __shared__ unsigned short Sh[16384];             // 32KB: 2x(As 4K + Bs 4K)
    unsigned short* T = Sh;                          // 128*72 epilogue transpose

    const int tid = threadIdx.x, lane = tid & 63, w = tid >> 6;
    const int quad = lane >> 4, c = lane & 15;
    const int wr = w >> 1, wc = w & 1;
    const int m0 = blockIdx.x * 128, n0 = blockIdx.y * 128;
    const int srow = lane >> 2;
    const int scol = ((lane & 3) ^ ((lane >> 3) & 3)) * 8;   // pre-swizzled src slot
    const int sA = (quad ^ ((c >> 1) & 3)) * 8;              // swizzled read slot

    f32x4 acc[4][4];
    #pragma unroll
    for (int i = 0; i < 4; i++)
        #pragma unroll
        for (int j = 0; j < 4; j++) acc[i][j] = (f32x4){0.f, 0.f, 0.f, 0.f};

    // ---- prologue: stage tile 0 into buffer 0 ----
    #pragma unroll
    for (int j = 0; j < 2; j++) {
        const int r = w * 32 + j * 16;
        GLDS16(Xb + (size_t)(m0 + r + srow) * 1024 + 0 + scol, &Sh[r * 32]);
        GLDS16(Wt + (size_t)(n0 + r + srow) * 1024 + 0 + scol, &Sh[4096 + r * 32]);
    }
    __syncthreads();

    int cur = 0;
    for (int t = 0; t < 32; ++t) {
        // issue next-tile loads into the other buffer (overlap with compute)
        if (t + 1 < 32) {
            const int kn = (t + 1) * 32;
            unsigned short* An = Sh + (cur ^ 1) * 8192;
            unsigned short* Bn = An + 4096;
            #pragma unroll
            for (int j = 0; j < 2; j++) {
                const int r = w * 32 + j * 16;
                GLDS16(Xb + (size_t)(m0 + r + srow) * 1024 + kn + scol, &An[r * 32]);
                GLDS16(Wt + (size_t)(n0 + r + srow) * 1024 + kn + scol, &Bn[r * 32]);
            }
        }
        const unsigned short* As = Sh + cur * 8192;
        const unsigned short* Bs = As + 4096;
        bf16x8 af[4], bf[4];
        #pragma unroll
        for (int rt = 0; rt < 4; rt++)
            af[rt] = *(const bf16x8*)&As[(wr * 64 + rt * 16 + c) * 32 + sA];
        #pragma unroll
        for (int nt = 0; nt < 4; nt++)
            bf[nt] = *(const bf16x8*)&Bs[(wc * 64 + nt * 16 + c) * 32 + sA];
        #pragma unroll
        for (int rt = 0; rt < 4; rt++)
            #pragma unroll
            for (int nt = 0; nt < 4; nt++)
                acc[rt][nt] = __builtin_amdgcn_mfma_f32_16x16x32_bf16(af[rt], bf[nt], acc[rt][nt], 0, 0, 0);
        __syncthreads();   // drains vmcnt(0): next buffer ready; cur reads done
        cur ^= 1;
    }

    float bv4[4];
    #pragma unroll
    for (int nt = 0; nt < 4; nt++) bv4[nt] = bias[n0 + wc * 64 + nt * 16 + c];

    if (z == 2) {
        const int b = m0 >> 11, sb = m0 & 2047;
        const int hgbase = n0 >> 6;
        #pragma unroll
        for (int h = 0; h < 2; h++) {
            if (wc == h) {
                #pragma unroll
                for (int rt = 0; rt < 4; rt++)
                    #pragma unroll
                    for (int reg = 0; reg < 4; reg++) {
                        const int s = wr * 64 + rt * 16 + quad * 4 + reg;
                        unsigned short u[4];
                        #pragma unroll
                        for (int nt = 0; nt < 4; nt++)
                            u[nt] = f2bf(acc[rt][nt][reg] + bv4[nt]);
                        *(int2*)&T[s * 72 + c * 4] = *(int2*)u;   // p = c*4+nt (sigma)
                    }
            }
            __syncthreads();
            const int p = tid >> 2, s8 = (tid & 3) * 32;
            unsigned short* dstb = Vtb + ((size_t)(b * 16 + hgbase + h) * 64 + p) * 2048 + sb;
            #pragma unroll
            for (int jj = 0; jj < 32; jj += 8) {
                unsigned short u[8];
                #pragma unroll
                for (int j = 0; j < 8; j++) u[j] = T[(s8 + jj + j) * 72 + p];
                *(int4*)(dstb + s8 + jj) = *(int4*)u;
            }
            __syncthreads();
        }
        return;
    }

    const float kLn = 9.210340371976184f / 32.0f;   // ln(10000)/32
    const float TWO_PI_INV = 0.15915494309189535f;
    const float rv0 = expf(-(float)c * kLn) * TWO_PI_INV;
    const float rv1 = expf(-(float)(c + 16) * kLn) * TWO_PI_INV;
    const float qscale = (z == 0) ? 0.125f : 1.0f;  // fold 1/sqrt(64) into Q

    #pragma unroll
    for (int rt = 0; rt < 4; rt++) {
        #pragma unroll
        for (int reg = 0; reg < 4; reg++) {
            const int m = m0 + wr * 64 + rt * 16 + quad * 4 + reg;
            const int b = m >> 11, s = m & 2047;
            float x0 = acc[rt][0][reg] + bv4[0];
            float x1 = acc[rt][1][reg] + bv4[1];
            float x2 = acc[rt][2][reg] + bv4[2];
            float x3 = acc[rt][3][reg] + bv4[3];
            float r0 = (float)s * rv0;  r0 -= floorf(r0);
            float r1 = (float)s * rv1;  r1 -= floorf(r1);
            const float sn0 = __builtin_amdgcn_sinf(r0);
            const float cs0 = __builtin_amdgcn_cosf(r0);
            const float sn1 = __builtin_amdgcn_sinf(r1);
            const float cs1 = __builtin_amdgcn_cosf(r1);
            const float y0 = (x0 * cs0 - x2 * sn0) * qscale;
            const float y2 = (x0 * sn0 + x2 * cs0) * qscale;
            const float y1 = (x1 * cs1 - x3 * sn1) * qscale;
            const float y3 = (x1 * sn1 + x3 * cs1) * qscale;
            const int h = (n0 + wc * 64) >> 6;
            unsigned short u[4] = { f2bf(y0), f2bf(y1), f2bf(y2), f2bf(y3) };
            unsigned short* dst = Out + ((size_t)(b * 16 + h) * 2048 + s) * 64;
            *(int2*)(dst + c * 4) = *(int2*)u;     // pi: pos c*4+nt
        }
    }
}

// ---------------------------------------------------------------------------
// Output projection GEMM, R19: R16 mechanism ported — 2-phase GLDS double-
// buffer + both-sides XOR slot-swizzle, one barrier per K-step. 64x128 tile,
// 512 blocks (2/CU), LDS 24KB.
// ---------------------------------------------------------------------------
__global__ __launch_bounds__(256)
void out_gemm(const unsigned short* __restrict__ Ab, const unsigned short* __restrict__ Wto,
              const float* __restrict__ bo, float* __restrict__ Out)
{
    __shared__ unsigned short Sh[12288];     // 24KB: 2 x (As 2048 + Bs 4096)
    const int tid = threadIdx.x, lane = tid & 63, w = tid >> 6;
    const int quad = lane >> 4, c = lane & 15;
    const int wr = w >> 1, wc = w & 1;
    const int m0 = blockIdx.x * 64, n0 = blockIdx.y * 128;
    const int srow = lane >> 2;
    const int scol = ((lane & 3) ^ ((lane >> 3) & 3)) * 8;   // pre-swizzled src slot
    const int sA = (quad ^ ((c >> 1) & 3)) * 8;              // swizzled read slot

    f32x4 acc[2][4];
    #pragma unroll
    for (int i = 0; i < 2; i++)
        #pragma unroll
        for (int j = 0; j < 4; j++) acc[i][j] = (f32x4){0.f, 0.f, 0.f, 0.f};

    // ---- prologue: stage tile 0 into buffer 0 ----
    GLDS16(Ab + (size_t)(m0 + w * 16 + srow) * 1024 + 0 + scol, &Sh[(w * 16) * 32]);
    #pragma unroll
    for (int j = 0; j < 2; j++) {
        const int r = w * 32 + j * 16;
        GLDS16(Wto + (size_t)(n0 + r + srow) * 1024 + 0 + scol, &Sh[2048 + r * 32]);
    }
    __syncthreads();

    int cur = 0;
    for (int t = 0; t < 32; ++t) {
        if (t + 1 < 32) {
            const int kn = (t + 1) * 32;
            unsigned short* An = Sh + (cur ^ 1) * 6144;
            unsigned short* Bn = An + 2048;
            GLDS16(Ab + (size_t)(m0 + w * 16 + srow) * 1024 + kn + scol, &An[(w * 16) * 32]);
            #pragma unroll
            for (int j = 0; j < 2; j++) {
                const int r = w * 32 + j * 16;
                GLDS16(Wto + (size_t)(n0 + r + srow) * 1024 + kn + scol, &Bn[r * 32]);
            }
        }
        const unsigned short* As = Sh + cur * 6144;
        const unsigned short* Bs = As + 2048;
        bf16x8 af[2], bf[4];
        #pragma unroll
        for (int rt = 0; rt < 2; rt++)
            af[rt] = *(const bf16x8*)&As[(wr * 32 + rt * 16 + c) * 32 + sA];
        #pragma unroll
        for (int nt = 0; nt < 4; nt++)
            bf[nt] = *(const bf16x8*)&Bs[(wc * 64 + nt * 16 + c) * 32 + sA];
        #pragma unroll
        for (int rt = 0; rt < 2; rt++)
            #pragma unroll
            for (int nt = 0; nt < 4; nt++)
                acc[rt][nt] = __builtin_amdgcn_mfma_f32_16x16x32_bf16(af[rt], bf[nt], acc[rt][nt], 0, 0, 0);
        __syncthreads();
        cur ^= 1;
    }
    #pragma unroll
    for (int rt = 0; rt < 2; rt++) {
        #pragma unroll
        for (int reg = 0; reg < 4; reg++) {
            const int m = m0 + wr * 32 + rt * 16 + quad * 4 + reg;
            #pragma unroll
            for (int nt = 0; nt < 4; nt++) {
                const int n = n0 + wc * 64 + nt * 16 + c;
                Out[(size_t)m * 1024 + n] = acc[rt][nt][reg] + bo[n];
            }
        }
    }
}

// ---------------------------------------------------------------------------
// Split-K flash attention, R19: R18 geometry (XT table, 20 chunks/bh) with
// SINGLE-BARRIER register-staged double-buffer. Iteration t: ds_write tile t
// into buf[cur] -> barrier -> issue loads(t+1) -> compute from buf[cur] ->
// cur^=1 (no trailing barrier). Safety: write(t+1) targets buf[cur^1], whose
// last reader compute(t-1) precedes write(t) in program order and is ordered
// across waves by barrier(t). Keeps register staging's long in-flight loads
// (R7 lesson: GLDS's vmcnt(0)-at-barrier kills overlap). LDS 36.9KB.
// ---------------------------------------------------------------------------
__global__ __launch_bounds__(512)
void attn_part(const unsigned short* __restrict__ Qb, const unsigned short* __restrict__ Kb,
               const unsigned short* __restrict__ Vtb, unsigned short* __restrict__ Ab,
               float* __restrict__ Opart, float* __restrict__ Lpart)
{
    __shared__ unsigned short Ks[2][64 * 72];   // [buf][key][d], pitch 144B
    __shared__ unsigned short Vs[2][64 * 72];   // [buf][p][key], pitch 144B

    const int tid = threadIdx.x, w = tid >> 6, lane = tid & 63;
    const int quad = lane >> 4, c = lane & 15;
    const int bh = blockIdx.y;
    const unsigned e = XT[blockIdx.x];
    const int i     = e & 7;
    const int start = (e >> 3) & 31;
    const int len   = (e >> 8) & 15;
    const int slot  = (e >> 12) & 31;
    const bool complete = (e >> 17) & 1;
    const int q0 = i * 256;
    const size_t base = (size_t)bh * 2048 * 64;

    bf16x8 on;                                  // bf16 1.0 x8 (ones column)
    #pragma unroll
    for (int ii = 0; ii < 8; ii++) on[ii] = (short)0x3F80;

    const int qbase = q0 + w * 32;              // wave owns rows [qbase, qbase+32)
    const size_t qoffA = base + (size_t)(qbase + c) * 64;
    const size_t qoffB = base + (size_t)(qbase + 16 + c) * 64;
    const bf16x8 qfA0 = *(const bf16x8*)(Qb + qoffA + quad * 8);
    const bf16x8 qfA1 = *(const bf16x8*)(Qb + qoffA + 32 + quad * 8);
    const bf16x8 qfB0 = *(const bf16x8*)(Qb + qoffB + quad * 8);
    const bf16x8 qfB1 = *(const bf16x8*)(Qb + qoffB + 32 + quad * 8);

    f32x4 OA[4], OB[4], OsA, OsB;
    OsA = (f32x4){0.f, 0.f, 0.f, 0.f};
    OsB = (f32x4){0.f, 0.f, 0.f, 0.f};
    #pragma unroll
    for (int nt = 0; nt < 4; nt++) { OA[nt] = OsA; OB[nt] = OsA; }

    // staging: 512 threads cover 64 rows x 64 elems (16B each) in one shot
    const int rs = tid >> 3, c8 = (tid & 7) * 8;

    int k0 = start * 64;
    int4 kreg = *(const int4*)(Kb  + base + (size_t)(k0 + rs) * 64 + c8);
    int4 vreg = *(const int4*)(Vtb + base + (size_t)rs * 2048 + k0 + c8);

    union P8 { bf16x8 v8; unsigned wd[4]; };
    union V8 { bf16x8 v8; bf16x4 v4[2]; };

    int cur = 0;
    for (int t = 0; t < len; t++, k0 += 64) {
        *(int4*)&Ks[cur][(size_t)rs * 72 + c8] = kreg;
        *(int4*)&Vs[cur][(size_t)rs * 72 + c8] = vreg;
        __syncthreads();

        if (t + 1 < len) {
            const int kn = k0 + 64;
            kreg = *(const int4*)(Kb  + base + (size_t)(kn + rs) * 64 + c8);
            vreg = *(const int4*)(Vtb + base + (size_t)rs * 2048 + kn + c8);
        }

        if (k0 <= qbase + 31) {                 // wave-uniform: else fully masked
            const int qrowA = qbase + c;
            const int qrowB = qbase + 16 + c;
            const bool nmA = (k0 + 63) > qbase;
            const bool nmB = (k0 + 63) > (qbase + 16);
            P8 paA0, paA1, paB0, paB1;
            __builtin_amdgcn_s_setprio(1);
            #pragma unroll
            for (int nt = 0; nt < 4; nt++) {
                const bf16x8 kf0 = *(const bf16x8*)&Ks[cur][(nt * 16 + c) * 72 + quad * 8];
                const bf16x8 kf1 = *(const bf16x8*)&Ks[cur][(nt * 16 + c) * 72 + 32 + quad * 8];
                f32x4 sA = (f32x4){0.f, 0.f, 0.f, 0.f};
                f32x4 sB = sA;
                sA = __builtin_amdgcn_mfma_f32_16x16x32_bf16(kf0, qfA0, sA, 0, 0, 0);
                sA = __builtin_amdgcn_mfma_f32_16x16x32_bf16(kf1, qfA1, sA, 0, 0, 0);
                sB = __builtin_amdgcn_mfma_f32_16x16x32_bf16(kf0, qfB0, sB, 0, 0, 0);
                sB = __builtin_amdgcn_mfma_f32_16x16x32_bf16(kf1, qfB1, sB, 0, 0, 0);
                const int keyb = k0 + nt * 16 + quad * 4;
                float pA[4], pB[4];
                #pragma unroll
                for (int reg = 0; reg < 4; reg++) {
                    float va = __expf(sA[reg]);           // Q pre-scaled by 0.125
                    if (nmA && (keyb + reg > qrowA)) va = 0.f;
                    pA[reg] = va;
                    float vb = __expf(sB[reg]);
                    if (nmB && (keyb + reg > qrowB)) vb = 0.f;
                    pB[reg] = vb;
                }
                const unsigned waA = cvt_pk_bf16(pA[0], pA[1]);
                const unsigned wbA = cvt_pk_bf16(pA[2], pA[3]);
                const unsigned waB = cvt_pk_bf16(pB[0], pB[1]);
                const unsigned wbB = cvt_pk_bf16(pB[2], pB[3]);
                // kappa mapping: frag (nt>>1), words 2*(nt&1)+{0,1}
                if (nt < 2) {
                    paA0.wd[2 * nt] = waA;     paA0.wd[2 * nt + 1] = wbA;
                    paB0.wd[2 * nt] = waB;     paB0.wd[2 * nt + 1] = wbB;
                } else {
                    paA1.wd[2 * (nt-2)] = waA; paA1.wd[2 * (nt-2) + 1] = wbA;
                    paB1.wd[2 * (nt-2)] = waB; paB1.wd[2 * (nt-2) + 1] = wbB;
                }
            }

            // ---- PV + row-sum; vb reads shared by both fragments ----
            #pragma unroll
            for (int nt = 0; nt < 4; nt++) {
                const int pr = (nt * 16 + c) * 72 + 4 * quad;
                V8 vb0, vb1;
                vb0.v4[0] = *(const bf16x4*)&Vs[cur][pr];
                vb0.v4[1] = *(const bf16x4*)&Vs[cur][pr + 16];
                vb1.v4[0] = *(const bf16x4*)&Vs[cur][pr + 32];
                vb1.v4[1] = *(const bf16x4*)&Vs[cur][pr + 48];
                OA[nt] = __builtin_amdgcn_mfma_f32_16x16x32_bf16(paA0.v8, vb0.v8, OA[nt], 0, 0, 0);
                OA[nt] = __builtin_amdgcn_mfma_f32_16x16x32_bf16(paA1.v8, vb1.v8, OA[nt], 0, 0, 0);
                OB[nt] = __builtin_amdgcn_mfma_f32_16x16x32_bf16(paB0.v8, vb0.v8, OB[nt], 0, 0, 0);
                OB[nt] = __builtin_amdgcn_mfma_f32_16x16x32_bf16(paB1.v8, vb1.v8, OB[nt], 0, 0, 0);
            }
            OsA = __builtin_amdgcn_mfma_f32_16x16x32_bf16(paA0.v8, on, OsA, 0, 0, 0);
            OsA = __builtin_amdgcn_mfma_f32_16x16x32_bf16(paA1.v8, on, OsA, 0, 0, 0);
            OsB = __builtin_amdgcn_mfma_f32_16x16x32_bf16(paB0.v8, on, OsB, 0, 0, 0);
            OsB = __builtin_amdgcn_mfma_f32_16x16x32_bf16(paB1.v8, on, OsB, 0, 0, 0);
            __builtin_amdgcn_s_setprio(0);
        }
        cur ^= 1;          // no trailing barrier: next write goes to other buf
    }

    if (complete) {
        const int b = bh >> 4, h = bh & 15;
        #pragma unroll
        for (int reg = 0; reg < 4; reg++) {
            const float invA = 1.0f / OsA[reg];
            const int qA = qbase + quad * 4 + reg;
            unsigned short uA[4];
            #pragma unroll
            for (int nt = 0; nt < 4; nt++) uA[nt] = f2bf(OA[nt][reg] * invA);
            unsigned short* dA = Ab + ((size_t)(b * 2048 + qA)) * 1024 + h * 64;
            *(int2*)(dA + c * 4) = *(int2*)uA;     // sigma: pos c*4+nt

            const float invB = 1.0f / OsB[reg];
            const int qB = qbase + 16 + quad * 4 + reg;
            unsigned short uB[4];
            #pragma unroll
            for (int nt = 0; nt < 4; nt++) uB[nt] = f2bf(OB[nt][reg] * invB);
            unsigned short* dB = Ab + ((size_t)(b * 2048 + qB)) * 1024 + h * 64;
            *(int2*)(dB + c * 4) = *(int2*)uB;
        }
    } else {
        float* Op = Opart + ((size_t)bh * 18 + slot) * 16384;
        float* Lp = Lpart + ((size_t)bh * 18 + slot) * 256;
        #pragma unroll
        for (int reg = 0; reg < 4; reg++) {
            const int rowA = w * 32 + quad * 4 + reg;       // [0,256)
            float4 oA = make_float4(OA[0][reg], OA[1][reg], OA[2][reg], OA[3][reg]);
            *(float4*)(Op + (size_t)rowA * 64 + c * 4) = oA;  // sigma order
            if (c == 0) Lp[rowA] = OsA[reg];

            const int rowB = rowA + 16;
            float4 oB = make_float4(OB[0][reg], OB[1][reg], OB[2][reg], OB[3][reg]);
            *(float4*)(Op + (size_t)rowB * 64 + c * 4) = oB;
            if (c == 0) Lp[rowB] = OsB[reg];
        }
    }
}

// ---------------------------------------------------------------------------
// Combine n in {2,3,4} partials per (bh, q-tile256 i=2..7). grid (12,32):
// j -> (i = 2 + j/2, half = j&1), 128 rows each. Slot base/count derived
// from i: sb = {0,2,4,7,10,14}, n = {2,2,3,3,4,4}.
// ---------------------------------------------------------------------------
__global__ __launch_bounds__(256)
void attn_combine(const float* __restrict__ Opart, const float* __restrict__ Lpart,
                  unsigned short* __restrict__ Ab)
{
    const int tid = threadIdx.x;
    const int j = blockIdx.x, bh = blockIdx.y;
    const int i = 2 + (j >> 1), half = j & 1;
    const int sb = (i < 4) ? 2 * (i - 2) : ((i < 6) ? 3 * i - 8 : 4 * i - 14);
    const int n  = (i < 4) ? 2 : ((i < 6) ? 3 : 4);
    const int q0 = i * 256 + half * 128;
    const size_t s0 = ((size_t)bh * 18 + sb) * 16384 + (size_t)half * 128 * 64;
    const size_t l0 = ((size_t)bh * 18 + sb) * 256 + half * 128;

    __shared__ float linv[128];
    if (tid < 128) {
        float l = 0.f;
        for (int s = 0; s < n; s++) l += Lpart[l0 + (size_t)s * 256 + tid];
        linv[tid] = 1.0f / l;
    }
    __syncthreads();

    const int row = tid >> 1, col0 = (tid & 1) * 32;
    const float inv = linv[row];
    const int b = bh >> 4, h = bh & 15;
    const int q = q0 + row;
    unsigned short* dst = Ab + ((size_t)(b * 2048 + q)) * 1024 + h * 64 + col0;
    #pragma unroll
    for (int c4 = 0; c4 < 32; c4 += 4) {
        float4 a = *(const float4*)(Opart + s0 + (size_t)row * 64 + col0 + c4);
        for (int s = 1; s < n; s++) {
            const float4 bb = *(const float4*)(Opart + s0 + (size_t)s * 16384 + (size_t)row * 64 + col0 + c4);
            a.x += bb.x; a.y += bb.y; a.z += bb.z; a.w += bb.w;
        }
        dst[c4 + 0] = f2bf(a.x * inv);
        dst[c4 + 1] = f2bf(a.y * inv);
        dst[c4 + 2] = f2bf(a.z * inv);
        dst[c4 + 3] = f2bf(a.w * inv);
    }
}

// ---------------------------------------------------------------------------
extern "C" void kernel_launch(void* const* d_in, const int* in_sizes, int n_in,
                              void* d_out, int out_size, void* d_ws, size_t ws_size,
                              hipStream_t stream)
{
    const float* X  = (const float*)d_in[0];
    const float* wq = (const float*)d_in[2];
    const float* bq = (const float*)d_in[3];
    const float* wk = (const float*)d_in[4];
    const float* bk = (const float*)d_in[5];
    const float* wv = (const float*)d_in[6];
    const float* bv = (const float*)d_in[7];
    const float* wo = (const float*)d_in[8];
    const float* bo = (const float*)d_in[9];

    unsigned short* ws = (unsigned short*)d_ws;
    const size_t M1 = 1024 * 1024;
    unsigned short* Xb  = ws;             // 4M elems
    unsigned short* Wtq = Xb  + 4 * M1;   // 1M each
    unsigned short* Wtk = Wtq + M1;
    unsigned short* Wtv = Wtk + M1;
    unsigned short* Wto = Wtv + M1;
    unsigned short* Qb  = Wto + M1;       // 4M each
    unsigned short* Kb  = Qb  + 4 * M1;
    unsigned short* Vtb = Kb  + 4 * M1;   // V^T written directly by qkv_gemm
    unsigned short* Ab  = Vtb + 4 * M1;   // bf16, 4M elems
    float* Opart = (float*)(Ab + 4 * M1); // 32*18*16384 fp32 = 37.75 MB
    float* Lpart = Opart + (size_t)32 * 18 * 16384;  // 147K fp32

    prep        <<<dim3(16, 16, 12), 256, 0, stream>>>(X, Xb, wq, wk, wv, wo,
                                                       Wtq, Wtk, Wtv, Wto);
    qkv_gemm    <<<dim3(32, 8, 3), 256, 0, stream>>>(Xb, Wtq, Wtk, Wtv, bq, bk, bv,
                                                     Qb, Kb, Vtb);
    attn_part   <<<dim3(20, 32), 512, 0, stream>>>(Qb, Kb, Vtb, Ab, Opart, Lpart);
    attn_combine<<<dim3(12, 32), 256, 0, stream>>>(Opart, Lpart, Ab);
    out_gemm    <<<dim3(64, 8), 256, 0, stream>>>(Ab, Wto, bo, (float*)d_out);
}

// Round 10
// 225.834 us; speedup vs baseline: 1.0231x; 1.0231x over previous
//
#include <hip/hip_runtime.h>
#include <math.h>

typedef short bf16x8 __attribute__((ext_vector_type(8)));
typedef short bf16x4 __attribute__((ext_vector_type(4)));
typedef float f32x4  __attribute__((ext_vector_type(4)));

__device__ __forceinline__ unsigned short f2bf(float f) {
    union { float f; unsigned u; } v; v.f = f;
    unsigned r = v.u + 0x7FFFu + ((v.u >> 16) & 1u);   // RNE
    return (unsigned short)(r >> 16);
}

__device__ __forceinline__ unsigned cvt_pk_bf16(float a, float b) {
    unsigned r;
    asm("v_cvt_pk_bf16_f32 %0, %1, %2" : "=v"(r) : "v"(a), "v"(b));
    return r;   // lo16 = bf16(a), hi16 = bf16(b), RNE
}

// async global->LDS, 16B per lane, LDS dest = wave-uniform base + lane*16B
#define GLDS16(gp, lp) __builtin_amdgcn_global_load_lds( \
    (const __attribute__((address_space(1))) void*)(gp), \
    (__attribute__((address_space(3))) void*)(lp), 16, 0, 0)

// Head-dim permutation: MFMA-C position (nt*16+c) stored at byte position
// (c*4+nt) within each 64-wide head block. Q,K share pi (dot invariant);
// V/Ab use sigma; Wto compensates. Q additionally pre-scaled by 0.125.

// attn split-K chunk table (R18): 20 blocks/bh, max len 8.
// entry = i | start<<3 | len<<8 | slot<<12 | complete<<17. Heavy-first.
__device__ const unsigned XT[20] = {
    59399u, 63559u, 67719u, 71879u,          // i7: s0/8/16/24 len8 slots14-17
    30725u, 34885u, 39045u,                  // i5: s0/8/16    len8 slots7-9
    10243u, 14403u,                          // i3: s0/8       len8 slots2-3
    133121u,                                 // i1: s0 len8 complete
    42758u, 46910u, 51062u, 55214u,          // i6: s0/7/14/21 len7 slots10-13
    18180u, 22332u,                          // i4: s0/7 len7  slots4-5
    26228u,                                  // i4: s14 len6   slot6
    1538u, 5682u,                            // i2: s0/6 len6  slots0-1
    132096u                                  // i0: s0 len4 complete
};

// ---------------------------------------------------------------------------
// prep: z<4 -> W fp32 [k][n] -> Wt bf16 [n][k] (z=3 un-permutes sigma(pi));
//       z>=4 -> X fp32 -> bf16 copy-convert
// ---------------------------------------------------------------------------
__global__ __launch_bounds__(256)
void prep(const float* __restrict__ X, unsigned short* __restrict__ Xb,
          const float* __restrict__ w0, const float* __restrict__ w1,
          const float* __restrict__ w2, const float* __restrict__ w3,
          unsigned short* o0, unsigned short* o1,
          unsigned short* o2, unsigned short* o3)
{
    const int z = blockIdx.z;
    if (z >= 4) {
        const int lb = (z - 4) * 256 + blockIdx.y * 16 + blockIdx.x;
        const size_t t = (size_t)lb * 256 + threadIdx.x;
        const float4 a = *(const float4*)(X + t * 8);
        const float4 b = *(const float4*)(X + t * 8 + 4);
        unsigned short u[8] = { f2bf(a.x), f2bf(a.y), f2bf(a.z), f2bf(a.w),
                                f2bf(b.x), f2bf(b.y), f2bf(b.z), f2bf(b.w) };
        *(int4*)(Xb + t * 8) = *(int4*)u;
        return;
    }
    const float* W; unsigned short* O;
    switch (z) {
        case 0: W = w0; O = o0; break;
        case 1: W = w1; O = o1; break;
        case 2: W = w2; O = o2; break;
        default: W = w3; O = o3; break;
    }
    __shared__ float T[64][65];
    const int tid = threadIdx.x;
    const int n0 = blockIdx.x * 64, k0 = blockIdx.y * 64;
    #pragma unroll
    for (int i = 0; i < 4; i++) {
        const int k = (tid >> 4) + i * 16, n4 = (tid & 15) * 4;
        const float4 v = *(const float4*)(W + (size_t)(k0 + k) * 1024 + n0 + n4);
        T[k][n4] = v.x; T[k][n4+1] = v.y; T[k][n4+2] = v.z; T[k][n4+3] = v.w;
    }
    __syncthreads();
    if (z == 3) {
        #pragma unroll
        for (int i = 0; i < 4; i++) {
            const int n = (tid >> 4) + i * 16, k4 = (tid & 15) * 4;
            unsigned short u[4];
            #pragma unroll
            for (int j = 0; j < 4; j++) {
                const int q = k4 + j;                      // Ab storage pos
                const int p = (q & 3) * 16 + (q >> 2);     // inv sigma
                const int d = (p & 3) * 16 + (p >> 2);     // inv pi
                u[j] = f2bf(T[d][n]);
            }
            *(int2*)(O + (size_t)(n0 + n) * 1024 + k0 + k4) = *(int2*)u;
        }
    } else {
        #pragma unroll
        for (int i = 0; i < 4; i++) {
            const int n = (tid >> 4) + i * 16, k4 = (tid & 15) * 4;
            unsigned short u[4] = { f2bf(T[k4][n]), f2bf(T[k4+1][n]),
                                    f2bf(T[k4+2][n]), f2bf(T[k4+3][n]) };
            *(int2*)(O + (size_t)(n0 + n) * 1024 + k0 + k4) = *(int2*)u;
        }
    }
}

// ---------------------------------------------------------------------------
// QKV GEMM (R16, unchanged): 128x128 tile, 2-phase GLDS double-buffer,
// XOR slot-swizzle both-sides, one barrier per K-step.
// ---------------------------------------------------------------------------
__global__ __launch_bounds__(256)
void qkv_gemm(const unsigned short* __restrict__ Xb,
              const unsigned short* __restrict__ Wtq, const unsigned short* __restrict__ Wtk,
              const unsigned short* __restrict__ Wtv,
              const float* __restrict__ bq, const float* __restrict__ bk,
              const float* __restrict__ bv,
              unsigned short* __restrict__ Qb, unsigned short* __restrict__ Kb,
              unsigned short* __restrict__ Vtb)
{
    const unsigned short* Wt; const float* bias; unsigned short* Out;
    const int z = blockIdx.z;
    if (z == 0)      { Wt = Wtq; bias = bq; Out = Qb; }
    else if (z == 1) { Wt = Wtk; bias = bk; Out = Kb; }
    else             { Wt = Wtv; bias = bv; Out = Vtb; }

    __shared__ unsigned short Sh[16384];             // 32KB: 2x(As 4K + Bs 4K)
    unsigned short* T = Sh;                          // 128*72 epilogue transpose

    const int tid = threadIdx.x, lane = tid & 63, w = tid >> 6;
    const int quad = lane >> 4, c = lane & 15;
    const int wr = w >> 1, wc = w & 1;
    const int m0 = blockIdx.x * 128, n0 = blockIdx.y * 128;
    const int srow = lane >> 2;
    const int scol = ((lane & 3) ^ ((lane >> 3) & 3)) * 8;   // pre-swizzled src slot
    const int sA = (quad ^ ((c >> 1) & 3)) * 8;              // swizzled read slot

    f32x4 acc[4][4];
    #pragma unroll
    for (int i = 0; i < 4; i++)
        #pragma unroll
        for (int j = 0; j < 4; j++) acc[i][j] = (f32x4){0.f, 0.f, 0.f, 0.f};

    // ---- prologue: stage tile 0 into buffer 0 ----
    #pragma unroll
    for (int j = 0; j < 2; j++) {
        const int r = w * 32 + j * 16;
        GLDS16(Xb + (size_t)(m0 + r + srow) * 1024 + 0 + scol, &Sh[r * 32]);
        GLDS16(Wt + (size_t)(n0 + r + srow) * 1024 + 0 + scol, &Sh[4096 + r * 32]);
    }
    __syncthreads();

    int cur = 0;
    for (int t = 0; t < 32; ++t) {
        // issue next-tile loads into the other buffer (overlap with compute)
        if (t + 1 < 32) {
            const int kn = (t + 1) * 32;
            unsigned short* An = Sh + (cur ^ 1) * 8192;
            unsigned short* Bn = An + 4096;
            #pragma unroll
            for (int j = 0; j < 2; j++) {
                const int r = w * 32 + j * 16;
                GLDS16(Xb + (size_t)(m0 + r + srow) * 1024 + kn + scol, &An[r * 32]);
                GLDS16(Wt + (size_t)(n0 + r + srow) * 1024 + kn + scol, &Bn[r * 32]);
            }
        }
        const unsigned short* As = Sh + cur * 8192;
        const unsigned short* Bs = As + 4096;
        bf16x8 af[4], bf[4];
        #pragma unroll
        for (int rt = 0; rt < 4; rt++)
            af[rt] = *(const bf16x8*)&As[(wr * 64 + rt * 16 + c) * 32 + sA];
        #pragma unroll
        for (int nt = 0; nt < 4; nt++)
            bf[nt] = *(const bf16x8*)&Bs[(wc * 64 + nt * 16 + c) * 32 + sA];
        #pragma unroll
        for (int rt = 0; rt < 4; rt++)
            #pragma unroll
            for (int nt = 0; nt < 4; nt++)
                acc[rt][nt] = __builtin_amdgcn_mfma_f32_16x16x32_bf16(af[rt], bf[nt], acc[rt][nt], 0, 0, 0);
        __syncthreads();   // drains vmcnt(0): next buffer ready; cur reads done
        cur ^= 1;
    }

    float bv4[4];
    #pragma unroll
    for (int nt = 0; nt < 4; nt++) bv4[nt] = bias[n0 + wc * 64 + nt * 16 + c];

    if (z == 2) {
        const int b = m0 >> 11, sb = m0 & 2047;
        const int hgbase = n0 >> 6;
        #pragma unroll
        for (int h = 0; h < 2; h++) {
            if (wc == h) {
                #pragma unroll
                for (int rt = 0; rt < 4; rt++)
                    #pragma unroll
                    for (int reg = 0; reg < 4; reg++) {
                        const int s = wr * 64 + rt * 16 + quad * 4 + reg;
                        unsigned short u[4];
                        #pragma unroll
                        for (int nt = 0; nt < 4; nt++)
                            u[nt] = f2bf(acc[rt][nt][reg] + bv4[nt]);
                        *(int2*)&T[s * 72 + c * 4] = *(int2*)u;   // p = c*4+nt (sigma)
                    }
            }
            __syncthreads();
            const int p = tid >> 2, s8 = (tid & 3) * 32;
            unsigned short* dstb = Vtb + ((size_t)(b * 16 + hgbase + h) * 64 + p) * 2048 + sb;
            #pragma unroll
            for (int jj = 0; jj < 32; jj += 8) {
                unsigned short u[8];
                #pragma unroll
                for (int j = 0; j < 8; j++) u[j] = T[(s8 + jj + j) * 72 + p];
                *(int4*)(dstb + s8 + jj) = *(int4*)u;
            }
            __syncthreads();
        }
        return;
    }

    const float kLn = 9.210340371976184f / 32.0f;   // ln(10000)/32
    const float TWO_PI_INV = 0.15915494309189535f;
    const float rv0 = expf(-(float)c * kLn) * TWO_PI_INV;
    const float rv1 = expf(-(float)(c + 16) * kLn) * TWO_PI_INV;
    const float qscale = (z == 0) ? 0.125f : 1.0f;  // fold 1/sqrt(64) into Q

    #pragma unroll
    for (int rt = 0; rt < 4; rt++) {
        #pragma unroll
        for (int reg = 0; reg < 4; reg++) {
            const int m = m0 + wr * 64 + rt * 16 + quad * 4 + reg;
            const int b = m >> 11, s = m & 2047;
            float x0 = acc[rt][0][reg] + bv4[0];
            float x1 = acc[rt][1][reg] + bv4[1];
            float x2 = acc[rt][2][reg] + bv4[2];
            float x3 = acc[rt][3][reg] + bv4[3];
            float r0 = (float)s * rv0;  r0 -= floorf(r0);
            float r1 = (float)s * rv1;  r1 -= floorf(r1);
            const float sn0 = __builtin_amdgcn_sinf(r0);
            const float cs0 = __builtin_amdgcn_cosf(r0);
            const float sn1 = __builtin_amdgcn_sinf(r1);
            const float cs1 = __builtin_amdgcn_cosf(r1);
            const float y0 = (x0 * cs0 - x2 * sn0) * qscale;
            const float y2 = (x0 * sn0 + x2 * cs0) * qscale;
            const float y1 = (x1 * cs1 - x3 * sn1) * qscale;
            const float y3 = (x1 * sn1 + x3 * cs1) * qscale;
            const int h = (n0 + wc * 64) >> 6;
            unsigned short u[4] = { f2bf(y0), f2bf(y1), f2bf(y2), f2bf(y3) };
            unsigned short* dst = Out + ((size_t)(b * 16 + h) * 2048 + s) * 64;
            *(int2*)(dst + c * 4) = *(int2*)u;     // pi: pos c*4+nt
        }
    }
}

// ---------------------------------------------------------------------------
// Output projection GEMM (R19, unchanged): 2-phase GLDS double-buffer +
// both-sides XOR slot-swizzle, one barrier per K-step. 64x128 tile.
// ---------------------------------------------------------------------------
__global__ __launch_bounds__(256)
void out_gemm(const unsigned short* __restrict__ Ab, const unsigned short* __restrict__ Wto,
              const float* __restrict__ bo, float* __restrict__ Out)
{
    __shared__ unsigned short Sh[12288];     // 24KB: 2 x (As 2048 + Bs 4096)
    const int tid = threadIdx.x, lane = tid & 63, w = tid >> 6;
    const int quad = lane >> 4, c = lane & 15;
    const int wr = w >> 1, wc = w & 1;
    const int m0 = blockIdx.x * 64, n0 = blockIdx.y * 128;
    const int srow = lane >> 2;
    const int scol = ((lane & 3) ^ ((lane >> 3) & 3)) * 8;   // pre-swizzled src slot
    const int sA = (quad ^ ((c >> 1) & 3)) * 8;              // swizzled read slot

    f32x4 acc[2][4];
    #pragma unroll
    for (int i = 0; i < 2; i++)
        #pragma unroll
        for (int j = 0; j < 4; j++) acc[i][j] = (f32x4){0.f, 0.f, 0.f, 0.f};

    // ---- prologue: stage tile 0 into buffer 0 ----
    GLDS16(Ab + (size_t)(m0 + w * 16 + srow) * 1024 + 0 + scol, &Sh[(w * 16) * 32]);
    #pragma unroll
    for (int j = 0; j < 2; j++) {
        const int r = w * 32 + j * 16;
        GLDS16(Wto + (size_t)(n0 + r + srow) * 1024 + 0 + scol, &Sh[2048 + r * 32]);
    }
    __syncthreads();

    int cur = 0;
    for (int t = 0; t < 32; ++t) {
        if (t + 1 < 32) {
            const int kn = (t + 1) * 32;
            unsigned short* An = Sh + (cur ^ 1) * 6144;
            unsigned short* Bn = An + 2048;
            GLDS16(Ab + (size_t)(m0 + w * 16 + srow) * 1024 + kn + scol, &An[(w * 16) * 32]);
            #pragma unroll
            for (int j = 0; j < 2; j++) {
                const int r = w * 32 + j * 16;
                GLDS16(Wto + (size_t)(n0 + r + srow) * 1024 + kn + scol, &Bn[r * 32]);
            }
        }
        const unsigned short* As = Sh + cur * 6144;
        const unsigned short* Bs = As + 2048;
        bf16x8 af[2], bf[4];
        #pragma unroll
        for (int rt = 0; rt < 2; rt++)
            af[rt] = *(const bf16x8*)&As[(wr * 32 + rt * 16 + c) * 32 + sA];
        #pragma unroll
        for (int nt = 0; nt < 4; nt++)
            bf[nt] = *(const bf16x8*)&Bs[(wc * 64 + nt * 16 + c) * 32 + sA];
        #pragma unroll
        for (int rt = 0; rt < 2; rt++)
            #pragma unroll
            for (int nt = 0; nt < 4; nt++)
                acc[rt][nt] = __builtin_amdgcn_mfma_f32_16x16x32_bf16(af[rt], bf[nt], acc[rt][nt], 0, 0, 0);
        __syncthreads();
        cur ^= 1;
    }
    #pragma unroll
    for (int rt = 0; rt < 2; rt++) {
        #pragma unroll
        for (int reg = 0; reg < 4; reg++) {
            const int m = m0 + wr * 32 + rt * 16 + quad * 4 + reg;
            #pragma unroll
            for (int nt = 0; nt < 4; nt++) {
                const int n = n0 + wc * 64 + nt * 16 + c;
                Out[(size_t)m * 1024 + n] = acc[rt][nt][reg] + bo[n];
            }
        }
    }
}

// ---------------------------------------------------------------------------
// Split-K flash attention (R18 revert — measured 41.9 us): register-staged
// K/V, 2 barriers/tile, single LDS set (18.4KB), XT 20-chunk table. R17
// (GLDS dbuf, -48%) and R19 (single-barrier dbuf, -17%) both falsified;
// this is the structural floor for this anatomy.
// ---------------------------------------------------------------------------
__global__ __launch_bounds__(512)
void attn_part(const unsigned short* __restrict__ Qb, const unsigned short* __restrict__ Kb,
               const unsigned short* __restrict__ Vtb, unsigned short* __restrict__ Ab,
               float* __restrict__ Opart, float* __restrict__ Lpart)
{
    __shared__ unsigned short Ks[64 * 72];      // [key][d], pitch 144B
    __shared__ unsigned short Vs[64 * 72];      // [p][key], pitch 144B

    const int tid = threadIdx.x, w = tid >> 6, lane = tid & 63;
    const int quad = lane >> 4, c = lane & 15;
    const int bh = blockIdx.y;
    const unsigned e = XT[blockIdx.x];
    const int i     = e & 7;
    const int start = (e >> 3) & 31;
    const int len   = (e >> 8) & 15;
    const int slot  = (e >> 12) & 31;
    const bool complete = (e >> 17) & 1;
    const int q0 = i * 256;
    const size_t base = (size_t)bh * 2048 * 64;

    bf16x8 on;                                  // bf16 1.0 x8 (ones column)
    #pragma unroll
    for (int ii = 0; ii < 8; ii++) on[ii] = (short)0x3F80;

    const int qbase = q0 + w * 32;              // wave owns rows [qbase, qbase+32)
    const size_t qoffA = base + (size_t)(qbase + c) * 64;
    const size_t qoffB = base + (size_t)(qbase + 16 + c) * 64;
    const bf16x8 qfA0 = *(const bf16x8*)(Qb + qoffA + quad * 8);
    const bf16x8 qfA1 = *(const bf16x8*)(Qb + qoffA + 32 + quad * 8);
    const bf16x8 qfB0 = *(const bf16x8*)(Qb + qoffB + quad * 8);
    const bf16x8 qfB1 = *(const bf16x8*)(Qb + qoffB + 32 + quad * 8);

    f32x4 OA[4], OB[4], OsA, OsB;
    OsA = (f32x4){0.f, 0.f, 0.f, 0.f};
    OsB = (f32x4){0.f, 0.f, 0.f, 0.f};
    #pragma unroll
    for (int nt = 0; nt < 4; nt++) { OA[nt] = OsA; OB[nt] = OsA; }

    // staging: 512 threads cover 64 rows x 64 elems (16B each) in one shot
    const int rs = tid >> 3, c8 = (tid & 7) * 8;

    int k0 = start * 64;
    int4 kreg = *(const int4*)(Kb  + base + (size_t)(k0 + rs) * 64 + c8);
    int4 vreg = *(const int4*)(Vtb + base + (size_t)rs * 2048 + k0 + c8);

    union P8 { bf16x8 v8; unsigned wd[4]; };
    union V8 { bf16x8 v8; bf16x4 v4[2]; };

    for (int t = 0; t < len; t++, k0 += 64) {
        *(int4*)&Ks[(size_t)rs * 72 + c8] = kreg;
        *(int4*)&Vs[(size_t)rs * 72 + c8] = vreg;
        __syncthreads();

        if (t + 1 < len) {
            const int kn = k0 + 64;
            kreg = *(const int4*)(Kb  + base + (size_t)(kn + rs) * 64 + c8);
            vreg = *(const int4*)(Vtb + base + (size_t)rs * 2048 + kn + c8);
        }

        if (k0 <= qbase + 31) {                 // wave-uniform: else fully masked
            const int qrowA = qbase + c;
            const int qrowB = qbase + 16 + c;
            const bool nmA = (k0 + 63) > qbase;
            const bool nmB = (k0 + 63) > (qbase + 16);
            P8 paA0, paA1, paB0, paB1;
            __builtin_amdgcn_s_setprio(1);
            #pragma unroll
            for (int nt = 0; nt < 4; nt++) {
                const bf16x8 kf0 = *(const bf16x8*)&Ks[(nt * 16 + c) * 72 + quad * 8];
                const bf16x8 kf1 = *(const bf16x8*)&Ks[(nt * 16 + c) * 72 + 32 + quad * 8];
                f32x4 sA = (f32x4){0.f, 0.f, 0.f, 0.f};
                f32x4 sB = sA;
                sA = __builtin_amdgcn_mfma_f32_16x16x32_bf16(kf0, qfA0, sA, 0, 0, 0);
                sA = __builtin_amdgcn_mfma_f32_16x16x32_bf16(kf1, qfA1, sA, 0, 0, 0);
                sB = __builtin_amdgcn_mfma_f32_16x16x32_bf16(kf0, qfB0, sB, 0, 0, 0);
                sB = __builtin_amdgcn_mfma_f32_16x16x32_bf16(kf1, qfB1, sB, 0, 0, 0);
                const int keyb = k0 + nt * 16 + quad * 4;
                float pA[4], pB[4];
                #pragma unroll
                for (int reg = 0; reg < 4; reg++) {
                    float va = __expf(sA[reg]);           // Q pre-scaled by 0.125
                    if (nmA && (keyb + reg > qrowA)) va = 0.f;
                    pA[reg] = va;
                    float vb = __expf(sB[reg]);
                    if (nmB && (keyb + reg > qrowB)) vb = 0.f;
                    pB[reg] = vb;
                }
                const unsigned waA = cvt_pk_bf16(pA[0], pA[1]);
                const unsigned wbA = cvt_pk_bf16(pA[2], pA[3]);
                const unsigned waB = cvt_pk_bf16(pB[0], pB[1]);
                const unsigned wbB = cvt_pk_bf16(pB[2], pB[3]);
                // kappa mapping: frag (nt>>1), words 2*(nt&1)+{0,1}
                if (nt < 2) {
                    paA0.wd[2 * nt] = waA;     paA0.wd[2 * nt + 1] = wbA;
                    paB0.wd[2 * nt] = waB;     paB0.wd[2 * nt + 1] = wbB;
                } else {
                    paA1.wd[2 * (nt-2)] = waA; paA1.wd[2 * (nt-2) + 1] = wbA;
                    paB1.wd[2 * (nt-2)] = waB; paB1.wd[2 * (nt-2) + 1] = wbB;
                }
            }

            // ---- PV + row-sum; vb reads shared by both fragments ----
            #pragma unroll
            for (int nt = 0; nt < 4; nt++) {
                const int pr = (nt * 16 + c) * 72 + 4 * quad;
                V8 vb0, vb1;
                vb0.v4[0] = *(const bf16x4*)&Vs[pr];
                vb0.v4[1] = *(const bf16x4*)&Vs[pr + 16];
                vb1.v4[0] = *(const bf16x4*)&Vs[pr + 32];
                vb1.v4[1] = *(const bf16x4*)&Vs[pr + 48];
                OA[nt] = __builtin_amdgcn_mfma_f32_16x16x32_bf16(paA0.v8, vb0.v8, OA[nt], 0, 0, 0);
                OA[nt] = __builtin_amdgcn_mfma_f32_16x16x32_bf16(paA1.v8, vb1.v8, OA[nt], 0, 0, 0);
                OB[nt] = __builtin_amdgcn_mfma_f32_16x16x32_bf16(paB0.v8, vb0.v8, OB[nt], 0, 0, 0);
                OB[nt] = __builtin_amdgcn_mfma_f32_16x16x32_bf16(paB1.v8, vb1.v8, OB[nt], 0, 0, 0);
            }
            OsA = __builtin_amdgcn_mfma_f32_16x16x32_bf16(paA0.v8, on, OsA, 0, 0, 0);
            OsA = __builtin_amdgcn_mfma_f32_16x16x32_bf16(paA1.v8, on, OsA, 0, 0, 0);
            OsB = __builtin_amdgcn_mfma_f32_16x16x32_bf16(paB0.v8, on, OsB, 0, 0, 0);
            OsB = __builtin_amdgcn_mfma_f32_16x16x32_bf16(paB1.v8, on, OsB, 0, 0, 0);
            __builtin_amdgcn_s_setprio(0);
        }
        __syncthreads();
    }

    if (complete) {
        const int b = bh >> 4, h = bh & 15;
        #pragma unroll
        for (int reg = 0; reg < 4; reg++) {
            const float invA = 1.0f / OsA[reg];
            const int qA = qbase + quad * 4 + reg;
            unsigned short uA[4];
            #pragma unroll
            for (int nt = 0; nt < 4; nt++) uA[nt] = f2bf(OA[nt][reg] * invA);
            unsigned short* dA = Ab + ((size_t)(b * 2048 + qA)) * 1024 + h * 64;
            *(int2*)(dA + c * 4) = *(int2*)uA;     // sigma: pos c*4+nt

            const float invB = 1.0f / OsB[reg];
            const int qB = qbase + 16 + quad * 4 + reg;
            unsigned short uB[4];
            #pragma unroll
            for (int nt = 0; nt < 4; nt++) uB[nt] = f2bf(OB[nt][reg] * invB);
            unsigned short* dB = Ab + ((size_t)(b * 2048 + qB)) * 1024 + h * 64;
            *(int2*)(dB + c * 4) = *(int2*)uB;
        }
    } else {
        float* Op = Opart + ((size_t)bh * 18 + slot) * 16384;
        float* Lp = Lpart + ((size_t)bh * 18 + slot) * 256;
        #pragma unroll
        for (int reg = 0; reg < 4; reg++) {
            const int rowA = w * 32 + quad * 4 + reg;       // [0,256)
            float4 oA = make_float4(OA[0][reg], OA[1][reg], OA[2][reg], OA[3][reg]);
            *(float4*)(Op + (size_t)rowA * 64 + c * 4) = oA;  // sigma order
            if (c == 0) Lp[rowA] = OsA[reg];

            const int rowB = rowA + 16;
            float4 oB = make_float4(OB[0][reg], OB[1][reg], OB[2][reg], OB[3][reg]);
            *(float4*)(Op + (size_t)rowB * 64 + c * 4) = oB;
            if (c == 0) Lp[rowB] = OsB[reg];
        }
    }
}

// ---------------------------------------------------------------------------
// Combine n in {2,3,4} partials per (bh, q-tile256 i=2..7). grid (12,32):
// j -> (i = 2 + j/2, half = j&1), 128 rows each. Slot base/count derived
// from i: sb = {0,2,4,7,10,14}, n = {2,2,3,3,4,4}.
// ---------------------------------------------------------------------------
__global__ __launch_bounds__(256)
void attn_combine(const float* __restrict__ Opart, const float* __restrict__ Lpart,
                  unsigned short* __restrict__ Ab)
{
    const int tid = threadIdx.x;
    const int j = blockIdx.x, bh = blockIdx.y;
    const int i = 2 + (j >> 1), half = j & 1;
    const int sb = (i < 4) ? 2 * (i - 2) : ((i < 6) ? 3 * i - 8 : 4 * i - 14);
    const int n  = (i < 4) ? 2 : ((i < 6) ? 3 : 4);
    const int q0 = i * 256 + half * 128;
    const size_t s0 = ((size_t)bh * 18 + sb) * 16384 + (size_t)half * 128 * 64;
    const size_t l0 = ((size_t)bh * 18 + sb) * 256 + half * 128;

    __shared__ float linv[128];
    if (tid < 128) {
        float l = 0.f;
        for (int s = 0; s < n; s++) l += Lpart[l0 + (size_t)s * 256 + tid];
        linv[tid] = 1.0f / l;
    }
    __syncthreads();

    const int row = tid >> 1, col0 = (tid & 1) * 32;
    const float inv = linv[row];
    const int b = bh >> 4, h = bh & 15;
    const int q = q0 + row;
    unsigned short* dst = Ab + ((size_t)(b * 2048 + q)) * 1024 + h * 64 + col0;
    #pragma unroll
    for (int c4 = 0; c4 < 32; c4 += 4) {
        float4 a = *(const float4*)(Opart + s0 + (size_t)row * 64 + col0 + c4);
        for (int s = 1; s < n; s++) {
            const float4 bb = *(const float4*)(Opart + s0 + (size_t)s * 16384 + (size_t)row * 64 + col0 + c4);
            a.x += bb.x; a.y += bb.y; a.z += bb.z; a.w += bb.w;
        }
        dst[c4 + 0] = f2bf(a.x * inv);
        dst[c4 + 1] = f2bf(a.y * inv);
        dst[c4 + 2] = f2bf(a.z * inv);
        dst[c4 + 3] = f2bf(a.w * inv);
    }
}

// ---------------------------------------------------------------------------
extern "C" void kernel_launch(void* const* d_in, const int* in_sizes, int n_in,
                              void* d_out, int out_size, void* d_ws, size_t ws_size,
                              hipStream_t stream)
{
    const float* X  = (const float*)d_in[0];
    const float* wq = (const float*)d_in[2];
    const float* bq = (const float*)d_in[3];
    const float* wk = (const float*)d_in[4];
    const float* bk = (const float*)d_in[5];
    const float* wv = (const float*)d_in[6];
    const float* bv = (const float*)d_in[7];
    const float* wo = (const float*)d_in[8];
    const float* bo = (const float*)d_in[9];

    unsigned short* ws = (unsigned short*)d_ws;
    const size_t M1 = 1024 * 1024;
    unsigned short* Xb  = ws;             // 4M elems
    unsigned short* Wtq = Xb  + 4 * M1;   // 1M each
    unsigned short* Wtk = Wtq + M1;
    unsigned short* Wtv = Wtk + M1;
    unsigned short* Wto = Wtv + M1;
    unsigned short* Qb  = Wto + M1;       // 4M each
    unsigned short* Kb  = Qb  + 4 * M1;
    unsigned short* Vtb = Kb  + 4 * M1;   // V^T written directly by qkv_gemm
    unsigned short* Ab  = Vtb + 4 * M1;   // bf16, 4M elems
    float* Opart = (float*)(Ab + 4 * M1); // 32*18*16384 fp32 = 37.75 MB
    float* Lpart = Opart + (size_t)32 * 18 * 16384;  // 147K fp32

    prep        <<<dim3(16, 16, 12), 256, 0, stream>>>(X, Xb, wq, wk, wv, wo,
                                                       Wtq, Wtk, Wtv, Wto);
    qkv_gemm    <<<dim3(32, 8, 3), 256, 0, stream>>>(Xb, Wtq, Wtk, Wtv, bq, bk, bv,
                                                     Qb, Kb, Vtb);
    attn_part   <<<dim3(20, 32), 512, 0, stream>>>(Qb, Kb, Vtb, Ab, Opart, Lpart);
    attn_combine<<<dim3(12, 32), 256, 0, stream>>>(Opart, Lpart, Ab);
    out_gemm    <<<dim3(64, 8), 256, 0, stream>>>(Ab, Wto, bo, (float*)d_out);
}

// Round 11
// 220.808 us; speedup vs baseline: 1.0464x; 1.0228x over previous
//
#include <hip/hip_runtime.h>
#include <math.h>

typedef short bf16x8 __attribute__((ext_vector_type(8)));
typedef short bf16x4 __attribute__((ext_vector_type(4)));
typedef float f32x4  __attribute__((ext_vector_type(4)));

__device__ __forceinline__ unsigned short f2bf(float f) {
    union { float f; unsigned u; } v; v.f = f;
    unsigned r = v.u + 0x7FFFu + ((v.u >> 16) & 1u);   // RNE
    return (unsigned short)(r >> 16);
}

__device__ __forceinline__ unsigned cvt_pk_bf16(float a, float b) {
    unsigned r;
    asm("v_cvt_pk_bf16_f32 %0, %1, %2" : "=v"(r) : "v"(a), "v"(b));
    return r;   // lo16 = bf16(a), hi16 = bf16(b), RNE
}

#if __has_builtin(__builtin_amdgcn_exp2f)
#define EXP2(x) __builtin_amdgcn_exp2f(x)
#else
#define EXP2(x) exp2f(x)
#endif

// async global->LDS, 16B per lane, LDS dest = wave-uniform base + lane*16B
#define GLDS16(gp, lp) __builtin_amdgcn_global_load_lds( \
    (const __attribute__((address_space(1))) void*)(gp), \
    (__attribute__((address_space(3))) void*)(lp), 16, 0, 0)

// Head-dim permutation: MFMA-C position (nt*16+c) stored at byte position
// (c*4+nt) within each 64-wide head block. Q,K share pi (dot invariant);
// V/Ab use sigma; Wto compensates. Q pre-scaled by 0.125*log2(e) so attn
// uses raw v_exp (2^x) instead of __expf's mul+exp.

// attn split-K chunk table (R18): 20 blocks/bh, max len 8.
// entry = i | start<<3 | len<<8 | slot<<12 | complete<<17. Heavy-first.
__device__ const unsigned XT[20] = {
    59399u, 63559u, 67719u, 71879u,          // i7: s0/8/16/24 len8 slots14-17
    30725u, 34885u, 39045u,                  // i5: s0/8/16    len8 slots7-9
    10243u, 14403u,                          // i3: s0/8       len8 slots2-3
    133121u,                                 // i1: s0 len8 complete
    42758u, 46910u, 51062u, 55214u,          // i6: s0/7/14/21 len7 slots10-13
    18180u, 22332u,                          // i4: s0/7 len7  slots4-5
    26228u,                                  // i4: s14 len6   slot6
    1538u, 5682u,                            // i2: s0/6 len6  slots0-1
    132096u                                  // i0: s0 len4 complete
};

// ---------------------------------------------------------------------------
// prep: z<4 -> W fp32 [k][n] -> Wt bf16 [n][k] (z=3 un-permutes sigma(pi));
//       z>=4 -> X fp32 -> bf16 copy-convert
// ---------------------------------------------------------------------------
__global__ __launch_bounds__(256)
void prep(const float* __restrict__ X, unsigned short* __restrict__ Xb,
          const float* __restrict__ w0, const float* __restrict__ w1,
          const float* __restrict__ w2, const float* __restrict__ w3,
          unsigned short* o0, unsigned short* o1,
          unsigned short* o2, unsigned short* o3)
{
    const int z = blockIdx.z;
    if (z >= 4) {
        const int lb = (z - 4) * 256 + blockIdx.y * 16 + blockIdx.x;
        const size_t t = (size_t)lb * 256 + threadIdx.x;
        const float4 a = *(const float4*)(X + t * 8);
        const float4 b = *(const float4*)(X + t * 8 + 4);
        unsigned short u[8] = { f2bf(a.x), f2bf(a.y), f2bf(a.z), f2bf(a.w),
                                f2bf(b.x), f2bf(b.y), f2bf(b.z), f2bf(b.w) };
        *(int4*)(Xb + t * 8) = *(int4*)u;
        return;
    }
    const float* W; unsigned short* O;
    switch (z) {
        case 0: W = w0; O = o0; break;
        case 1: W = w1; O = o1; break;
        case 2: W = w2; O = o2; break;
        default: W = w3; O = o3; break;
    }
    __shared__ float T[64][65];
    const int tid = threadIdx.x;
    const int n0 = blockIdx.x * 64, k0 = blockIdx.y * 64;
    #pragma unroll
    for (int i = 0; i < 4; i++) {
        const int k = (tid >> 4) + i * 16, n4 = (tid & 15) * 4;
        const float4 v = *(const float4*)(W + (size_t)(k0 + k) * 1024 + n0 + n4);
        T[k][n4] = v.x; T[k][n4+1] = v.y; T[k][n4+2] = v.z; T[k][n4+3] = v.w;
    }
    __syncthreads();
    if (z == 3) {
        #pragma unroll
        for (int i = 0; i < 4; i++) {
            const int n = (tid >> 4) + i * 16, k4 = (tid & 15) * 4;
            unsigned short u[4];
            #pragma unroll
            for (int j = 0; j < 4; j++) {
                const int q = k4 + j;                      // Ab storage pos
                const int p = (q & 3) * 16 + (q >> 2);     // inv sigma
                const int d = (p & 3) * 16 + (p >> 2);     // inv pi
                u[j] = f2bf(T[d][n]);
            }
            *(int2*)(O + (size_t)(n0 + n) * 1024 + k0 + k4) = *(int2*)u;
        }
    } else {
        #pragma unroll
        for (int i = 0; i < 4; i++) {
            const int n = (tid >> 4) + i * 16, k4 = (tid & 15) * 4;
            unsigned short u[4] = { f2bf(T[k4][n]), f2bf(T[k4+1][n]),
                                    f2bf(T[k4+2][n]), f2bf(T[k4+3][n]) };
            *(int2*)(O + (size_t)(n0 + n) * 1024 + k0 + k4) = *(int2*)u;
        }
    }
}

// ---------------------------------------------------------------------------
// QKV GEMM (R16 structure): 128x128 tile, 2-phase GLDS double-buffer,
// XOR slot-swizzle both-sides, one barrier per K-step. R21: Q prescale now
// 0.125*log2(e) (exp2 fold).
// ---------------------------------------------------------------------------
__global__ __launch_bounds__(256)
void qkv_gemm(const unsigned short* __restrict__ Xb,
              const unsigned short* __restrict__ Wtq, const unsigned short* __restrict__ Wtk,
              const unsigned short* __restrict__ Wtv,
              const float* __restrict__ bq, const float* __restrict__ bk,
              const float* __restrict__ bv,
              unsigned short* __restrict__ Qb, unsigned short* __restrict__ Kb,
              unsigned short* __restrict__ Vtb)
{
    const unsigned short* Wt; const float* bias; unsigned short* Out;
    const int z = blockIdx.z;
    if (z == 0)      { Wt = Wtq; bias = bq; Out = Qb; }
    else if (z == 1) { Wt = Wtk; bias = bk; Out = Kb; }
    else             { Wt = Wtv; bias = bv; Out = Vtb; }

    __shared__ unsigned short Sh[16384];             // 32KB: 2x(As 4K + Bs 4K)
    unsigned short* T = Sh;                          // 128*72 epilogue transpose

    const int tid = threadIdx.x, lane = tid & 63, w = tid >> 6;
    const int quad = lane >> 4, c = lane & 15;
    const int wr = w >> 1, wc = w & 1;
    const int m0 = blockIdx.x * 128, n0 = blockIdx.y * 128;
    const int srow = lane >> 2;
    const int scol = ((lane & 3) ^ ((lane >> 3) & 3)) * 8;   // pre-swizzled src slot
    const int sA = (quad ^ ((c >> 1) & 3)) * 8;              // swizzled read slot

    f32x4 acc[4][4];
    #pragma unroll
    for (int i = 0; i < 4; i++)
        #pragma unroll
        for (int j = 0; j < 4; j++) acc[i][j] = (f32x4){0.f, 0.f, 0.f, 0.f};

    // ---- prologue: stage tile 0 into buffer 0 ----
    #pragma unroll
    for (int j = 0; j < 2; j++) {
        const int r = w * 32 + j * 16;
        GLDS16(Xb + (size_t)(m0 + r + srow) * 1024 + 0 + scol, &Sh[r * 32]);
        GLDS16(Wt + (size_t)(n0 + r + srow) * 1024 + 0 + scol, &Sh[4096 + r * 32]);
    }
    __syncthreads();

    int cur = 0;
    for (int t = 0; t < 32; ++t) {
        // issue next-tile loads into the other buffer (overlap with compute)
        if (t + 1 < 32) {
            const int kn = (t + 1) * 32;
            unsigned short* An = Sh + (cur ^ 1) * 8192;
            unsigned short* Bn = An + 4096;
            #pragma unroll
            for (int j = 0; j < 2; j++) {
                const int r = w * 32 + j * 16;
                GLDS16(Xb + (size_t)(m0 + r + srow) * 1024 + kn + scol, &An[r * 32]);
                GLDS16(Wt + (size_t)(n0 + r + srow) * 1024 + kn + scol, &Bn[r * 32]);
            }
        }
        const unsigned short* As = Sh + cur * 8192;
        const unsigned short* Bs = As + 4096;
        bf16x8 af[4], bf[4];
        #pragma unroll
        for (int rt = 0; rt < 4; rt++)
            af[rt] = *(const bf16x8*)&As[(wr * 64 + rt * 16 + c) * 32 + sA];
        #pragma unroll
        for (int nt = 0; nt < 4; nt++)
            bf[nt] = *(const bf16x8*)&Bs[(wc * 64 + nt * 16 + c) * 32 + sA];
        #pragma unroll
        for (int rt = 0; rt < 4; rt++)
            #pragma unroll
            for (int nt = 0; nt < 4; nt++)
                acc[rt][nt] = __builtin_amdgcn_mfma_f32_16x16x32_bf16(af[rt], bf[nt], acc[rt][nt], 0, 0, 0);
        __syncthreads();   // drains vmcnt(0): next buffer ready; cur reads done
        cur ^= 1;
    }

    float bv4[4];
    #pragma unroll
    for (int nt = 0; nt < 4; nt++) bv4[nt] = bias[n0 + wc * 64 + nt * 16 + c];

    if (z == 2) {
        const int b = m0 >> 11, sb = m0 & 2047;
        const int hgbase = n0 >> 6;
        #pragma unroll
        for (int h = 0; h < 2; h++) {
            if (wc == h) {
                #pragma unroll
                for (int rt = 0; rt < 4; rt++)
                    #pragma unroll
                    for (int reg = 0; reg < 4; reg++) {
                        const int s = wr * 64 + rt * 16 + quad * 4 + reg;
                        unsigned short u[4];
                        #pragma unroll
                        for (int nt = 0; nt < 4; nt++)
                            u[nt] = f2bf(acc[rt][nt][reg] + bv4[nt]);
                        *(int2*)&T[s * 72 + c * 4] = *(int2*)u;   // p = c*4+nt (sigma)
                    }
            }
            __syncthreads();
            const int p = tid >> 2, s8 = (tid & 3) * 32;
            unsigned short* dstb = Vtb + ((size_t)(b * 16 + hgbase + h) * 64 + p) * 2048 + sb;
            #pragma unroll
            for (int jj = 0; jj < 32; jj += 8) {
                unsigned short u[8];
                #pragma unroll
                for (int j = 0; j < 8; j++) u[j] = T[(s8 + jj + j) * 72 + p];
                *(int4*)(dstb + s8 + jj) = *(int4*)u;
            }
            __syncthreads();
        }
        return;
    }

    const float kLn = 9.210340371976184f / 32.0f;   // ln(10000)/32
    const float TWO_PI_INV = 0.15915494309189535f;
    const float rv0 = expf(-(float)c * kLn) * TWO_PI_INV;
    const float rv1 = expf(-(float)(c + 16) * kLn) * TWO_PI_INV;
    // fold 1/sqrt(64) AND log2(e) into Q so attn uses raw v_exp (2^x)
    const float qscale = (z == 0) ? 0.125f * 1.4426950408889634f : 1.0f;

    #pragma unroll
    for (int rt = 0; rt < 4; rt++) {
        #pragma unroll
        for (int reg = 0; reg < 4; reg++) {
            const int m = m0 + wr * 64 + rt * 16 + quad * 4 + reg;
            const int b = m >> 11, s = m & 2047;
            float x0 = acc[rt][0][reg] + bv4[0];
            float x1 = acc[rt][1][reg] + bv4[1];
            float x2 = acc[rt][2][reg] + bv4[2];
            float x3 = acc[rt][3][reg] + bv4[3];
            float r0 = (float)s * rv0;  r0 -= floorf(r0);
            float r1 = (float)s * rv1;  r1 -= floorf(r1);
            const float sn0 = __builtin_amdgcn_sinf(r0);
            const float cs0 = __builtin_amdgcn_cosf(r0);
            const float sn1 = __builtin_amdgcn_sinf(r1);
            const float cs1 = __builtin_amdgcn_cosf(r1);
            const float y0 = (x0 * cs0 - x2 * sn0) * qscale;
            const float y2 = (x0 * sn0 + x2 * cs0) * qscale;
            const float y1 = (x1 * cs1 - x3 * sn1) * qscale;
            const float y3 = (x1 * sn1 + x3 * cs1) * qscale;
            const int h = (n0 + wc * 64) >> 6;
            unsigned short u[4] = { f2bf(y0), f2bf(y1), f2bf(y2), f2bf(y3) };
            unsigned short* dst = Out + ((size_t)(b * 16 + h) * 2048 + s) * 64;
            *(int2*)(dst + c * 4) = *(int2*)u;     // pi: pos c*4+nt
        }
    }
}

// ---------------------------------------------------------------------------
// Output projection GEMM (R19, unchanged): 2-phase GLDS double-buffer +
// both-sides XOR slot-swizzle, one barrier per K-step. 64x128 tile.
// ---------------------------------------------------------------------------
__global__ __launch_bounds__(256)
void out_gemm(const unsigned short* __restrict__ Ab, const unsigned short* __restrict__ Wto,
              const float* __restrict__ bo, float* __restrict__ Out)
{
    __shared__ unsigned short Sh[12288];     // 24KB: 2 x (As 2048 + Bs 4096)
    const int tid = threadIdx.x, lane = tid & 63, w = tid >> 6;
    const int quad = lane >> 4, c = lane & 15;
    const int wr = w >> 1, wc = w & 1;
    const int m0 = blockIdx.x * 64, n0 = blockIdx.y * 128;
    const int srow = lane >> 2;
    const int scol = ((lane & 3) ^ ((lane >> 3) & 3)) * 8;   // pre-swizzled src slot
    const int sA = (quad ^ ((c >> 1) & 3)) * 8;              // swizzled read slot

    f32x4 acc[2][4];
    #pragma unroll
    for (int i = 0; i < 2; i++)
        #pragma unroll
        for (int j = 0; j < 4; j++) acc[i][j] = (f32x4){0.f, 0.f, 0.f, 0.f};

    // ---- prologue: stage tile 0 into buffer 0 ----
    GLDS16(Ab + (size_t)(m0 + w * 16 + srow) * 1024 + 0 + scol, &Sh[(w * 16) * 32]);
    #pragma unroll
    for (int j = 0; j < 2; j++) {
        const int r = w * 32 + j * 16;
        GLDS16(Wto + (size_t)(n0 + r + srow) * 1024 + 0 + scol, &Sh[2048 + r * 32]);
    }
    __syncthreads();

    int cur = 0;
    for (int t = 0; t < 32; ++t) {
        if (t + 1 < 32) {
            const int kn = (t + 1) * 32;
            unsigned short* An = Sh + (cur ^ 1) * 6144;
            unsigned short* Bn = An + 2048;
            GLDS16(Ab + (size_t)(m0 + w * 16 + srow) * 1024 + kn + scol, &An[(w * 16) * 32]);
            #pragma unroll
            for (int j = 0; j < 2; j++) {
                const int r = w * 32 + j * 16;
                GLDS16(Wto + (size_t)(n0 + r + srow) * 1024 + kn + scol, &Bn[r * 32]);
            }
        }
        const unsigned short* As = Sh + cur * 6144;
        const unsigned short* Bs = As + 2048;
        bf16x8 af[2], bf[4];
        #pragma unroll
        for (int rt = 0; rt < 2; rt++)
            af[rt] = *(const bf16x8*)&As[(wr * 32 + rt * 16 + c) * 32 + sA];
        #pragma unroll
        for (int nt = 0; nt < 4; nt++)
            bf[nt] = *(const bf16x8*)&Bs[(wc * 64 + nt * 16 + c) * 32 + sA];
        #pragma unroll
        for (int rt = 0; rt < 2; rt++)
            #pragma unroll
            for (int nt = 0; nt < 4; nt++)
                acc[rt][nt] = __builtin_amdgcn_mfma_f32_16x16x32_bf16(af[rt], bf[nt], acc[rt][nt], 0, 0, 0);
        __syncthreads();
        cur ^= 1;
    }
    #pragma unroll
    for (int rt = 0; rt < 2; rt++) {
        #pragma unroll
        for (int reg = 0; reg < 4; reg++) {
            const int m = m0 + wr * 32 + rt * 16 + quad * 4 + reg;
            #pragma unroll
            for (int nt = 0; nt < 4; nt++) {
                const int n = n0 + wc * 64 + nt * 16 + c;
                Out[(size_t)m * 1024 + n] = acc[rt][nt][reg] + bo[n];
            }
        }
    }
}

// ---------------------------------------------------------------------------
// Split-K flash attention (R18 structure — the measured floor for this
// anatomy). R21 adds: (1) bijective XCD swizzle so each XCD's L2 keeps a few
// bh's K/V resident (640 = 8 x 80; xcd = flat%8 gets 80 consecutive flat ids
// = 4 bh) — targets cold-load latency on the per-tile serial chain;
// (2) raw v_exp (2^x) — log2e pre-folded into Q by qkv_gemm.
// ---------------------------------------------------------------------------
__global__ __launch_bounds__(512)
void attn_part(const unsigned short* __restrict__ Qb, const unsigned short* __restrict__ Kb,
               const unsigned short* __restrict__ Vtb, unsigned short* __restrict__ Ab,
               float* __restrict__ Opart, float* __restrict__ Lpart)
{
    __shared__ unsigned short Ks[64 * 72];      // [key][d], pitch 144B
    __shared__ unsigned short Vs[64 * 72];      // [p][key], pitch 144B

    const int tid = threadIdx.x, w = tid >> 6, lane = tid & 63;
    const int quad = lane >> 4, c = lane & 15;

    // XCD-aware bijective remap: 640 blocks, x fastest in HW dispatch order
    const int flat = blockIdx.y * 20 + blockIdx.x;
    const int nf = (flat & 7) * 80 + (flat >> 3);
    const int bh = nf / 20;
    const unsigned e = XT[nf % 20];

    const int i     = e & 7;
    const int start = (e >> 3) & 31;
    const int len   = (e >> 8) & 15;
    const int slot  = (e >> 12) & 31;
    const bool complete = (e >> 17) & 1;
    const int q0 = i * 256;
    const size_t base = (size_t)bh * 2048 * 64;

    bf16x8 on;                                  // bf16 1.0 x8 (ones column)
    #pragma unroll
    for (int ii = 0; ii < 8; ii++) on[ii] = (short)0x3F80;

    const int qbase = q0 + w * 32;              // wave owns rows [qbase, qbase+32)
    const size_t qoffA = base + (size_t)(qbase + c) * 64;
    const size_t qoffB = base + (size_t)(qbase + 16 + c) * 64;
    const bf16x8 qfA0 = *(const bf16x8*)(Qb + qoffA + quad * 8);
    const bf16x8 qfA1 = *(const bf16x8*)(Qb + qoffA + 32 + quad * 8);
    const bf16x8 qfB0 = *(const bf16x8*)(Qb + qoffB + quad * 8);
    const bf16x8 qfB1 = *(const bf16x8*)(Qb + qoffB + 32 + quad * 8);

    f32x4 OA[4], OB[4], OsA, OsB;
    OsA = (f32x4){0.f, 0.f, 0.f, 0.f};
    OsB = (f32x4){0.f, 0.f, 0.f, 0.f};
    #pragma unroll
    for (int nt = 0; nt < 4; nt++) { OA[nt] = OsA; OB[nt] = OsA; }

    // staging: 512 threads cover 64 rows x 64 elems (16B each) in one shot
    const int rs = tid >> 3, c8 = (tid & 7) * 8;

    int k0 = start * 64;
    int4 kreg = *(const int4*)(Kb  + base + (size_t)(k0 + rs) * 64 + c8);
    int4 vreg = *(const int4*)(Vtb + base + (size_t)rs * 2048 + k0 + c8);

    union P8 { bf16x8 v8; unsigned wd[4]; };
    union V8 { bf16x8 v8; bf16x4 v4[2]; };

    for (int t = 0; t < len; t++, k0 += 64) {
        *(int4*)&Ks[(size_t)rs * 72 + c8] = kreg;
        *(int4*)&Vs[(size_t)rs * 72 + c8] = vreg;
        __syncthreads();

        if (t + 1 < len) {
            const int kn = k0 + 64;
            kreg = *(const int4*)(Kb  + base + (size_t)(kn + rs) * 64 + c8);
            vreg = *(const int4*)(Vtb + base + (size_t)rs * 2048 + kn + c8);
        }

        if (k0 <= qbase + 31) {                 // wave-uniform: else fully masked
            const int qrowA = qbase + c;
            const int qrowB = qbase + 16 + c;
            const bool nmA = (k0 + 63) > qbase;
            const bool nmB = (k0 + 63) > (qbase + 16);
            P8 paA0, paA1, paB0, paB1;
            __builtin_amdgcn_s_setprio(1);
            #pragma unroll
            for (int nt = 0; nt < 4; nt++) {
                const bf16x8 kf0 = *(const bf16x8*)&Ks[(nt * 16 + c) * 72 + quad * 8];
                const bf16x8 kf1 = *(const bf16x8*)&Ks[(nt * 16 + c) * 72 + 32 + quad * 8];
                f32x4 sA = (f32x4){0.f, 0.f, 0.f, 0.f};
                f32x4 sB = sA;
                sA = __builtin_amdgcn_mfma_f32_16x16x32_bf16(kf0, qfA0, sA, 0, 0, 0);
                sA = __builtin_amdgcn_mfma_f32_16x16x32_bf16(kf1, qfA1, sA, 0, 0, 0);
                sB = __builtin_amdgcn_mfma_f32_16x16x32_bf16(kf0, qfB0, sB, 0, 0, 0);
                sB = __builtin_amdgcn_mfma_f32_16x16x32_bf16(kf1, qfB1, sB, 0, 0, 0);
                const int keyb = k0 + nt * 16 + quad * 4;
                float pA[4], pB[4];
                #pragma unroll
                for (int reg = 0; reg < 4; reg++) {
                    float va = EXP2(sA[reg]);             // Q pre-scaled by 0.125*log2e
                    if (nmA && (keyb + reg > qrowA)) va = 0.f;
                    pA[reg] = va;
                    float vb = EXP2(sB[reg]);
                    if (nmB && (keyb + reg > qrowB)) vb = 0.f;
                    pB[reg] = vb;
                }
                const unsigned waA = cvt_pk_bf16(pA[0], pA[1]);
                const unsigned wbA = cvt_pk_bf16(pA[2], pA[3]);
                const unsigned waB = cvt_pk_bf16(pB[0], pB[1]);
                const unsigned wbB = cvt_pk_bf16(pB[2], pB[3]);
                // kappa mapping: frag (nt>>1), words 2*(nt&1)+{0,1}
                if (nt < 2) {
                    paA0.wd[2 * nt] = waA;     paA0.wd[2 * nt + 1] = wbA;
                    paB0.wd[2 * nt] = waB;     paB0.wd[2 * nt + 1] = wbB;
                } else {
                    paA1.wd[2 * (nt-2)] = waA; paA1.wd[2 * (nt-2) + 1] = wbA;
                    paB1.wd[2 * (nt-2)] = waB; paB1.wd[2 * (nt-2) + 1] = wbB;
                }
            }

            // ---- PV + row-sum; vb reads shared by both fragments ----
            #pragma unroll
            for (int nt = 0; nt < 4; nt++) {
                const int pr = (nt * 16 + c) * 72 + 4 * quad;
                V8 vb0, vb1;
                vb0.v4[0] = *(const bf16x4*)&Vs[pr];
                vb0.v4[1] = *(const bf16x4*)&Vs[pr + 16];
                vb1.v4[0] = *(const bf16x4*)&Vs[pr + 32];
                vb1.v4[1] = *(const bf16x4*)&Vs[pr + 48];
                OA[nt] = __builtin_amdgcn_mfma_f32_16x16x32_bf16(paA0.v8, vb0.v8, OA[nt], 0, 0, 0);
                OA[nt] = __builtin_amdgcn_mfma_f32_16x16x32_bf16(paA1.v8, vb1.v8, OA[nt], 0, 0, 0);
                OB[nt] = __builtin_amdgcn_mfma_f32_16x16x32_bf16(paB0.v8, vb0.v8, OB[nt], 0, 0, 0);
                OB[nt] = __builtin_amdgcn_mfma_f32_16x16x32_bf16(paB1.v8, vb1.v8, OB[nt], 0, 0, 0);
            }
            OsA = __builtin_amdgcn_mfma_f32_16x16x32_bf16(paA0.v8, on, OsA, 0, 0, 0);
            OsA = __builtin_amdgcn_mfma_f32_16x16x32_bf16(paA1.v8, on, OsA, 0, 0, 0);
            OsB = __builtin_amdgcn_mfma_f32_16x16x32_bf16(paB0.v8, on, OsB, 0, 0, 0);
            OsB = __builtin_amdgcn_mfma_f32_16x16x32_bf16(paB1.v8, on, OsB, 0, 0, 0);
            __builtin_amdgcn_s_setprio(0);
        }
        __syncthreads();
    }

    if (complete) {
        const int b = bh >> 4, h = bh & 15;
        #pragma unroll
        for (int reg = 0; reg < 4; reg++) {
            const float invA = 1.0f / OsA[reg];
            const int qA = qbase + quad * 4 + reg;
            unsigned short uA[4];
            #pragma unroll
            for (int nt = 0; nt < 4; nt++) uA[nt] = f2bf(OA[nt][reg] * invA);
            unsigned short* dA = Ab + ((size_t)(b * 2048 + qA)) * 1024 + h * 64;
            *(int2*)(dA + c * 4) = *(int2*)uA;     // sigma: pos c*4+nt

            const float invB = 1.0f / OsB[reg];
            const int qB = qbase + 16 + quad * 4 + reg;
            unsigned short uB[4];
            #pragma unroll
            for (int nt = 0; nt < 4; nt++) uB[nt] = f2bf(OB[nt][reg] * invB);
            unsigned short* dB = Ab + ((size_t)(b * 2048 + qB)) * 1024 + h * 64;
            *(int2*)(dB + c * 4) = *(int2*)uB;
        }
    } else {
        float* Op = Opart + ((size_t)bh * 18 + slot) * 16384;
        float* Lp = Lpart + ((size_t)bh * 18 + slot) * 256;
        #pragma unroll
        for (int reg = 0; reg < 4; reg++) {
            const int rowA = w * 32 + quad * 4 + reg;       // [0,256)
            float4 oA = make_float4(OA[0][reg], OA[1][reg], OA[2][reg], OA[3][reg]);
            *(float4*)(Op + (size_t)rowA * 64 + c * 4) = oA;  // sigma order
            if (c == 0) Lp[rowA] = OsA[reg];

            const int rowB = rowA + 16;
            float4 oB = make_float4(OB[0][reg], OB[1][reg], OB[2][reg], OB[3][reg]);
            *(float4*)(Op + (size_t)rowB * 64 + c * 4) = oB;
            if (c == 0) Lp[rowB] = OsB[reg];
        }
    }
}

// ---------------------------------------------------------------------------
// Combine n in {2,3,4} partials per (bh, q-tile256 i=2..7). grid (12,32):
// j -> (i = 2 + j/2, half = j&1), 128 rows each. Slot base/count derived
// from i: sb = {0,2,4,7,10,14}, n = {2,2,3,3,4,4}.
// ---------------------------------------------------------------------------
__global__ __launch_bounds__(256)
void attn_combine(const float* __restrict__ Opart, const float* __restrict__ Lpart,
                  unsigned short* __restrict__ Ab)
{
    const int tid = threadIdx.x;
    const int j = blockIdx.x, bh = blockIdx.y;
    const int i = 2 + (j >> 1), half = j & 1;
    const int sb = (i < 4) ? 2 * (i - 2) : ((i < 6) ? 3 * i - 8 : 4 * i - 14);
    const int n  = (i < 4) ? 2 : ((i < 6) ? 3 : 4);
    const int q0 = i * 256 + half * 128;
    const size_t s0 = ((size_t)bh * 18 + sb) * 16384 + (size_t)half * 128 * 64;
    const size_t l0 = ((size_t)bh * 18 + sb) * 256 + half * 128;

    __shared__ float linv[128];
    if (tid < 128) {
        float l = 0.f;
        for (int s = 0; s < n; s++) l += Lpart[l0 + (size_t)s * 256 + tid];
        linv[tid] = 1.0f / l;
    }
    __syncthreads();

    const int row = tid >> 1, col0 = (tid & 1) * 32;
    const float inv = linv[row];
    const int b = bh >> 4, h = bh & 15;
    const int q = q0 + row;
    unsigned short* dst = Ab + ((size_t)(b * 2048 + q)) * 1024 + h * 64 + col0;
    #pragma unroll
    for (int c4 = 0; c4 < 32; c4 += 4) {
        float4 a = *(const float4*)(Opart + s0 + (size_t)row * 64 + col0 + c4);
        for (int s = 1; s < n; s++) {
            const float4 bb = *(const float4*)(Opart + s0 + (size_t)s * 16384 + (size_t)row * 64 + col0 + c4);
            a.x += bb.x; a.y += bb.y; a.z += bb.z; a.w += bb.w;
        }
        dst[c4 + 0] = f2bf(a.x * inv);
        dst[c4 + 1] = f2bf(a.y * inv);
        dst[c4 + 2] = f2bf(a.z * inv);
        dst[c4 + 3] = f2bf(a.w * inv);
    }
}

// ---------------------------------------------------------------------------
extern "C" void kernel_launch(void* const* d_in, const int* in_sizes, int n_in,
                              void* d_out, int out_size, void* d_ws, size_t ws_size,
                              hipStream_t stream)
{
    const float* X  = (const float*)d_in[0];
    const float* wq = (const float*)d_in[2];
    const float* bq = (const float*)d_in[3];
    const float* wk = (const float*)d_in[4];
    const float* bk = (const float*)d_in[5];
    const float* wv = (const float*)d_in[6];
    const float* bv = (const float*)d_in[7];
    const float* wo = (const float*)d_in[8];
    const float* bo = (const float*)d_in[9];

    unsigned short* ws = (unsigned short*)d_ws;
    const size_t M1 = 1024 * 1024;
    unsigned short* Xb  = ws;             // 4M elems
    unsigned short* Wtq = Xb  + 4 * M1;   // 1M each
    unsigned short* Wtk = Wtq + M1;
    unsigned short* Wtv = Wtk + M1;
    unsigned short* Wto = Wtv + M1;
    unsigned short* Qb  = Wto + M1;       // 4M each
    unsigned short* Kb  = Qb  + 4 * M1;
    unsigned short* Vtb = Kb  + 4 * M1;   // V^T written directly by qkv_gemm
    unsigned short* Ab  = Vtb + 4 * M1;   // bf16, 4M elems
    float* Opart = (float*)(Ab + 4 * M1); // 32*18*16384 fp32 = 37.75 MB
    float* Lpart = Opart + (size_t)32 * 18 * 16384;  // 147K fp32

    prep        <<<dim3(16, 16, 12), 256, 0, stream>>>(X, Xb, wq, wk, wv, wo,
                                                       Wtq, Wtk, Wtv, Wto);
    qkv_gemm    <<<dim3(32, 8, 3), 256, 0, stream>>>(Xb, Wtq, Wtk, Wtv, bq, bk, bv,
                                                     Qb, Kb, Vtb);
    attn_part   <<<dim3(20, 32), 512, 0, stream>>>(Qb, Kb, Vtb, Ab, Opart, Lpart);
    attn_combine<<<dim3(12, 32), 256, 0, stream>>>(Opart, Lpart, Ab);
    out_gemm    <<<dim3(64, 8), 256, 0, stream>>>(Ab, Wto, bo, (float*)d_out);
}